// Round 10
// baseline (147.087 us; speedup 1.0000x reference)
//
#include <hip/hip_runtime.h>
#include <cstdint>
#include <cstddef>

#define DEV __device__ __forceinline__

typedef __bf16 bf16x8 __attribute__((ext_vector_type(8)));
typedef float f32x4 __attribute__((ext_vector_type(4)));
typedef unsigned short us8 __attribute__((ext_vector_type(8)));
typedef unsigned short us4 __attribute__((ext_vector_type(4)));

typedef const __attribute__((address_space(1))) unsigned int GUI;
typedef __attribute__((address_space(3))) unsigned int LUI;

DEV unsigned short f2bf(float f) {
  unsigned int u = __builtin_bit_cast(unsigned int, f);
  u += 0x7fffu + ((u >> 16) & 1u);
  return (unsigned short)(u >> 16);
}
DEV float bf2f(unsigned short h) {
  unsigned int u = ((unsigned int)h) << 16;
  return __builtin_bit_cast(float, u);
}

// ---------- fused prep: z->bf16, weight transposes, bias concat ----------
DEV void tr32(const float* __restrict__ in, unsigned short* __restrict__ out,
              int K, int N, int k0, int n0) {
  __shared__ float tile[32][33];
  const int tx = threadIdx.x & 31, ty = threadIdx.x >> 5;  // 256 thr = 32x8
#pragma unroll
  for (int i = 0; i < 32; i += 8)
    tile[ty + i][tx] = in[(size_t)(k0 + ty + i) * N + n0 + tx];
  __syncthreads();
#pragma unroll
  for (int i = 0; i < 32; i += 8)
    out[(size_t)(n0 + ty + i) * K + k0 + tx] = f2bf(tile[tx][ty + i]);
}

__global__ __launch_bounds__(256) void k_prep(
    const float* __restrict__ z, unsigned short* __restrict__ zb,
    const float* __restrict__ Wq, const float* __restrict__ Wk,
    const float* __restrict__ Wv, const float* __restrict__ Wo,
    unsigned short* __restrict__ Wsq,
    const float* __restrict__ W1, unsigned short* __restrict__ W1T,
    const float* __restrict__ W2, unsigned short* __restrict__ W2T,
    const float* __restrict__ bq, const float* __restrict__ bk,
    const float* __restrict__ bv, float* __restrict__ biasqkv) {
  const int j = blockIdx.x;
  const int tid = threadIdx.x;
  if (j < 4096) {
    int i = j * 256 + tid;
    float4 v = ((const float4*)z)[i];
    us4 o;
    o.x = f2bf(v.x); o.y = f2bf(v.y); o.z = f2bf(v.z); o.w = f2bf(v.w);
    *(us4*)(zb + (size_t)i * 4) = o;
  } else if (j < 5120) {
    int t = j - 4096;
    int mat = t >> 8, tile = t & 255;
    const float* in = mat == 0 ? Wq : mat == 1 ? Wk : mat == 2 ? Wv : Wo;
    tr32(in, Wsq + (size_t)mat * 262144, 512, 512, (tile >> 4) * 32, (tile & 15) * 32);
  } else if (j < 6144) {
    int t = j - 5120;
    tr32(W1, W1T, 512, 2048, (t / 64) * 32, (t % 64) * 32);
  } else if (j < 7168) {
    int t = j - 6144;
    tr32(W2, W2T, 2048, 512, (t / 16) * 32, (t % 16) * 32);
  } else {
    for (int i = tid; i < 1536; i += 256)
      biasqkv[i] = (i < 512) ? bq[i] : (i < 1024 ? bk[i - 512] : bv[i - 1024]);
  }
}

// --------- bf16 MFMA GEMM body: 256x256 tile, BK=32, 4-slot ring,
// fine 2-phase-per-K-tile interleave with COUNTED vmcnt (never 0 mid-loop).
// ph1(t): {8 A + 4 B ds_read(t)} || {stage A(t+3)} -> bar -> lgkm0 -> 16 MFMA(mh0) -> bar
// ph2(t): {4 A ds_read(t)}      || {stage B(t+3)} -> vmcnt(8) [t+1 ready; 2 tiles
//         stay in flight] -> bar -> lgkm0 -> 16 MFMA(mh1) -> bar
// Ring safety: stage of t+3 targets slot (t-1)&3, whose reads all retired
// before t's ph1 barrier. Tile-t readiness established at t-1's ph2 vmcnt,
// one barrier before t's first ds_read.
// LDS layout (round-7 verified): global row r, k-chunk q lives at LDS row
// R=r>>1 (128B rows), chunk d=((r&1)*4+q)^(R&7) -> gload_lds-linear dests,
// conflict-free ds_read_b128.
template <int MODE, int SPLITK>
DEV void gemm_body(const unsigned short* __restrict__ A,
                   const unsigned short* __restrict__ BT,
                   const float* __restrict__ bias,
                   unsigned short* __restrict__ outp,
                   int K, int N) {
  __shared__ __align__(16) unsigned short As[4 * 8192];
  __shared__ __align__(16) unsigned short Bs[4 * 8192];
  const int tid = threadIdx.x;
  const int wave = tid >> 6, lane = tid & 63;
  const int wm = wave >> 2, wn = wave & 3;
  const int q = lane >> 4, l15 = lane & 15;

  // XCD-bijective block swizzle, A-panel-grouped ((bx,z) fastest)
  const int nx = gridDim.x, ny = gridDim.y;
  const int nwg = nx * ny * SPLITK;
  const int lid = (blockIdx.z * ny + blockIdx.y) * nx + blockIdx.x;
  const int q8 = nwg >> 3, r8 = nwg & 7;
  const int xcd = lid & 7, slot0 = lid >> 3;
  const int wid = (xcd < r8 ? xcd * (q8 + 1) : r8 * (q8 + 1) + (xcd - r8) * q8) + slot0;
  const int nbz = nx * SPLITK;
  const int bxz = wid % nbz;
  const int by  = wid / nbz;
  const int bx  = bxz % nx;
  const int z   = bxz / nx;

  const int rbase = by * 256;
  const int nbase = bx * 256;
  const int nkt = (K / SPLITK) >> 5;       // K-steps of 32 (>=4 at all call sites)
  const int kb = z * (K / SPLITK);

  float bv_[4];
#pragma unroll
  for (int n = 0; n < 4; ++n) {
    int gcol = nbase + wn * 64 + n * 16 + l15;
    bv_[n] = (z == 0) ? bias[gcol] : 0.f;
  }
  asm volatile("s_waitcnt vmcnt(0)" ::: "memory");

  // ---- precomputed per-thread staging state (2 A + 2 B loads / tile) ----
  const unsigned short* pA[2];
  const unsigned short* pB[2];
  int dstL[2];
#pragma unroll
  for (int i = 0; i < 2; ++i) {
    int s = i * 512 + tid;                 // 16B-slot in [0,1024)
    int R = s >> 3;                        // lds-row 0..127
    int c = (s & 7) ^ (R & 7);             // source data-chunk for linear dest
    int r = 2 * R + (c >> 2);              // global tile row 0..255
    int kl = (c & 3) << 3;                 // k offset 0..24
    pA[i] = A + (size_t)(rbase + r) * K + kb + kl;
    pB[i] = BT + (size_t)(nbase + r) * K + kb + kl;
    dstL[i] = (i * 512 + wave * 64) * 8;   // wave-uniform dest base (elements)
  }
  const unsigned short* pA0 = pA[0]; const unsigned short* pA1 = pA[1];
  const unsigned short* pB0 = pB[0]; const unsigned short* pB1 = pB[1];

#define STAGE_A(SLOT)                                                                     \
  __builtin_amdgcn_global_load_lds((GUI*)pA0, (LUI*)(As + (SLOT) * 8192 + dstL[0]), 16, 0, 0); \
  __builtin_amdgcn_global_load_lds((GUI*)pA1, (LUI*)(As + (SLOT) * 8192 + dstL[1]), 16, 0, 0); \
  pA0 += 32; pA1 += 32;
#define STAGE_B(SLOT)                                                                     \
  __builtin_amdgcn_global_load_lds((GUI*)pB0, (LUI*)(Bs + (SLOT) * 8192 + dstL[0]), 16, 0, 0); \
  __builtin_amdgcn_global_load_lds((GUI*)pB1, (LUI*)(Bs + (SLOT) * 8192 + dstL[1]), 16, 0, 0); \
  pB0 += 32; pB1 += 32;

  // ---- precomputed ds_read offsets (elements) ----
  int aoff[8], boff[4];
#pragma unroll
  for (int m = 0; m < 8; ++m) {
    int rr = wm * 128 + m * 16 + l15;
    int R = rr >> 1;
    int d = (((rr & 1) << 2) + q) ^ (R & 7);
    aoff[m] = R * 64 + d * 8;
  }
#pragma unroll
  for (int n = 0; n < 4; ++n) {
    int rr = wn * 64 + n * 16 + l15;
    int R = rr >> 1;
    int d = (((rr & 1) << 2) + q) ^ (R & 7);
    boff[n] = R * 64 + d * 8;
  }

  f32x4 acc[8][4] = {};
  bf16x8 af[4], bfr[4];

  // prologue: stage tiles 0,1,2 (12 loads); tile 0 ready when <=8 outstanding
  STAGE_A(0) STAGE_B(0)
  STAGE_A(1) STAGE_B(1)
  STAGE_A(2) STAGE_B(2)
  asm volatile("s_waitcnt vmcnt(8)" ::: "memory");
  __builtin_amdgcn_s_barrier();

#define MFMA16(MH)                                                                 \
  _Pragma("unroll") for (int m = 0; m < 4; ++m)                                    \
  _Pragma("unroll") for (int n = 0; n < 4; ++n)                                    \
    acc[(MH) * 4 + m][n] =                                                         \
        __builtin_amdgcn_mfma_f32_16x16x32_bf16(af[m], bfr[n], acc[(MH) * 4 + m][n], 0, 0, 0);

  for (int t = 0; t < nkt; ++t) {
    const int slot = t & 3;
    const unsigned short* Ab = As + slot * 8192;
    const unsigned short* Bb = Bs + slot * 8192;
    const bool pre = (t + 3 < nkt);
    const int nslot = (t + 3) & 3;

    // ---- phase 1: reads(t, mh0) + stage A(t+3) ----
#pragma unroll
    for (int m = 0; m < 4; ++m)
      af[m] = __builtin_bit_cast(bf16x8, *(const us8*)(Ab + aoff[m]));
#pragma unroll
    for (int n = 0; n < 4; ++n)
      bfr[n] = __builtin_bit_cast(bf16x8, *(const us8*)(Bb + boff[n]));
    if (pre) { STAGE_A(nslot) }
    __builtin_amdgcn_s_barrier();
    asm volatile("s_waitcnt lgkmcnt(0)" ::: "memory");
    __builtin_amdgcn_sched_barrier(0);
    __builtin_amdgcn_s_setprio(1);
    MFMA16(0)
    __builtin_amdgcn_s_setprio(0);
    __builtin_amdgcn_s_barrier();

    // ---- phase 2: reads(t, mh1) + stage B(t+3) + counted vmcnt (t+1 ready) ----
#pragma unroll
    for (int m = 0; m < 4; ++m)
      af[m] = __builtin_bit_cast(bf16x8, *(const us8*)(Ab + aoff[4 + m]));
    if (pre) {
      STAGE_B(nslot)
      asm volatile("s_waitcnt vmcnt(8)" ::: "memory");   // t+1 landed; t+2,t+3 in flight
    } else if (t + 2 < nkt) {
      asm volatile("s_waitcnt vmcnt(4)" ::: "memory");   // t+1 landed; t+2 in flight
    } else if (t + 1 < nkt) {
      asm volatile("s_waitcnt vmcnt(0)" ::: "memory");   // final tile ready
    }
    __builtin_amdgcn_s_barrier();
    asm volatile("s_waitcnt lgkmcnt(0)" ::: "memory");
    __builtin_amdgcn_sched_barrier(0);
    __builtin_amdgcn_s_setprio(1);
    MFMA16(1)
    __builtin_amdgcn_s_setprio(0);
    __builtin_amdgcn_s_barrier();
  }
#undef MFMA16
#undef STAGE_A
#undef STAGE_B

  unsigned short* opv = outp + (size_t)z * 8192 * N;
#pragma unroll
  for (int m = 0; m < 8; ++m) {
    int grow0 = rbase + wm * 128 + m * 16 + (q << 2);
#pragma unroll
    for (int n = 0; n < 4; ++n) {
      int gcol = nbase + wn * 64 + n * 16 + l15;
#pragma unroll
      for (int r = 0; r < 4; ++r) {
        float v = acc[m][n][r] + bv_[n];
        if (MODE == 2) v = 0.5f * v * (1.0f + erff(v * 0.70710678118654752f));
        opv[(size_t)(grow0 + r) * N + gcol] = f2bf(v);
      }
    }
  }
}

__global__ __launch_bounds__(512) void k_qkv(const unsigned short* __restrict__ A,
                                             const unsigned short* __restrict__ BT,
                                             const float* __restrict__ bias,
                                             unsigned short* __restrict__ outp, int K, int N) {
  gemm_body<0, 1>(A, BT, bias, outp, K, N);
}
__global__ __launch_bounds__(512) void k_wo(const unsigned short* __restrict__ A,
                                            const unsigned short* __restrict__ BT,
                                            const float* __restrict__ bias,
                                            unsigned short* __restrict__ outp, int K, int N) {
  gemm_body<0, 4>(A, BT, bias, outp, K, N);
}
__global__ __launch_bounds__(512) void k_ffn1(const unsigned short* __restrict__ A,
                                              const unsigned short* __restrict__ BT,
                                              const float* __restrict__ bias,
                                              unsigned short* __restrict__ outp, int K, int N) {
  gemm_body<2, 1>(A, BT, bias, outp, K, N);
}
__global__ __launch_bounds__(512) void k_ffn2(const unsigned short* __restrict__ A,
                                              const unsigned short* __restrict__ BT,
                                              const float* __restrict__ bias,
                                              unsigned short* __restrict__ outp, int K, int N) {
  gemm_body<0, 4>(A, BT, bias, outp, K, N);
}

// ---------------- windowed causal attention -----------------------
__global__ __launch_bounds__(64) void k_attn(const unsigned short* __restrict__ qkv,
                                             unsigned short* __restrict__ attnb) {
  __shared__ float Qt[64 * 35];
  __shared__ float Kt[64 * 45];
  __shared__ float P[32 * 12];

  const int lane = threadIdx.x;
  const int bid = blockIdx.x;          // 2048 = 64 chunks x 32 bh
  const int chunk = bid & 63;
  const int bh = bid >> 6;
  const int h = bh & 7, b = bh >> 3;
  const int i0 = chunk * 32;
  const int b2048 = b * 2048;
  const int h64 = h * 64;

#pragma unroll 8
  for (int r = 0; r < 41; ++r) {
    int jloc = i0 - 9 + r;
    int jc = jloc < 0 ? 0 : jloc;
    Kt[lane * 45 + r] = bf2f(qkv[(size_t)(b2048 + jc) * 1536 + 512 + h64 + lane]);
  }
#pragma unroll 8
  for (int r = 0; r < 32; ++r) {
    Qt[lane * 35 + r] = bf2f(qkv[(size_t)(b2048 + i0 + r) * 1536 + h64 + lane]);
  }
  __syncthreads();

  const int qe = lane & 31, dh = lane >> 5;
  float s[10];
#pragma unroll
  for (int jj = 0; jj < 10; ++jj) s[jj] = 0.f;
#pragma unroll
  for (int dd = 0; dd < 32; ++dd) {
    int d = dh * 32 + dd;
    float qd = Qt[d * 35 + qe];
#pragma unroll
    for (int jj = 0; jj < 10; ++jj)
      s[jj] = fmaf(qd, Kt[d * 45 + qe + jj], s[jj]);
  }
#pragma unroll
  for (int jj = 0; jj < 10; ++jj) s[jj] += __shfl_xor(s[jj], 32);

  const int iG = i0 + qe;
#pragma unroll
  for (int jj = 0; jj < 10; ++jj)
    s[jj] = (iG - 9 + jj >= 0) ? s[jj] * 0.125f : -1e30f;
  float mx = s[9];
#pragma unroll
  for (int jj = 0; jj < 9; ++jj) mx = fmaxf(mx, s[jj]);
  float den = 0.f;
#pragma unroll
  for (int jj = 0; jj < 10; ++jj) {
    s[jj] = __expf(s[jj] - mx);
    den += s[jj];
  }
  float inv = 1.f / den;
  if (lane < 32) {
#pragma unroll
    for (int jj = 0; jj < 10; ++jj) P[qe * 12 + jj] = s[jj] * inv;
  }
  __syncthreads();

  for (int q0 = 0; q0 < 32; q0 += 4) {
    float vv[13];
#pragma unroll
    for (int t = 0; t < 13; ++t) {
      int jloc = i0 + q0 - 9 + t;
      int jc = jloc < 0 ? 0 : jloc;
      vv[t] = bf2f(qkv[(size_t)(b2048 + jc) * 1536 + 1024 + h64 + lane]);
    }
#pragma unroll
    for (int qq = 0; qq < 4; ++qq) {
      const int qy = q0 + qq;
      const float* pp = &P[qy * 12];
      float o = 0.f;
#pragma unroll
      for (int jj = 0; jj < 10; ++jj) o = fmaf(pp[jj], vv[qq + jj], o);
      attnb[(size_t)(b2048 + i0 + qy) * 512 + h64 + lane] = f2bf(o);
    }
  }
}

// ---------------- residual + LayerNorm ----------------------------
template <int OUTF32, int NP>
DEV void ln_body(const unsigned short* __restrict__ res,
                 const unsigned short* __restrict__ add,
                 const float* __restrict__ w,
                 const float* __restrict__ bb,
                 void* __restrict__ outp) {
  const size_t PLANE = (size_t)8192 * 512;
  const int wave = threadIdx.x >> 6, lane = threadIdx.x & 63;
  const int row = blockIdx.x * 4 + wave;
  float x[8];
  us8 r = *(const us8*)(res + (size_t)row * 512 + lane * 8);
#pragma unroll
  for (int j = 0; j < 8; ++j) x[j] = bf2f(r[j]);
#pragma unroll
  for (int p = 0; p < NP; ++p) {
    us8 a = *(const us8*)(add + p * PLANE + (size_t)row * 512 + lane * 8);
#pragma unroll
    for (int j = 0; j < 8; ++j) x[j] += bf2f(a[j]);
  }
  float sum = 0.f, ss = 0.f;
#pragma unroll
  for (int j = 0; j < 8; ++j) {
    sum += x[j];
    ss += x[j] * x[j];
  }
#pragma unroll
  for (int m = 32; m >= 1; m >>= 1) {
    sum += __shfl_xor(sum, m);
    ss += __shfl_xor(ss, m);
  }
  const float mu = sum * (1.f / 512.f);
  float var = ss * (1.f / 512.f) - mu * mu;
  const float rstd = rsqrtf(var + 1e-5f);
  const int c = lane * 8;
  float o[8];
#pragma unroll
  for (int j = 0; j < 8; ++j) o[j] = (x[j] - mu) * rstd * w[c + j] + bb[c + j];
  if (OUTF32 == 0) {
    us8 u;
#pragma unroll
    for (int j = 0; j < 8; ++j) u[j] = f2bf(o[j]);
    *(us8*)((unsigned short*)outp + (size_t)row * 512 + c) = u;
  } else {
    float4 u0, u1;
    u0.x = o[0]; u0.y = o[1]; u0.z = o[2]; u0.w = o[3];
    u1.x = o[4]; u1.y = o[5]; u1.z = o[6]; u1.w = o[7];
    float4* o4 = (float4*)((float*)outp + (size_t)row * 512 + c);
    o4[0] = u0; o4[1] = u1;
  }
}

__global__ __launch_bounds__(256) void k_ln_mid(const unsigned short* __restrict__ res,
                                                const unsigned short* __restrict__ add,
                                                const float* __restrict__ w,
                                                const float* __restrict__ bb,
                                                unsigned short* __restrict__ outp) {
  ln_body<0, 4>(res, add, w, bb, outp);
}
__global__ __launch_bounds__(256) void k_ln_out(const unsigned short* __restrict__ res,
                                                const unsigned short* __restrict__ add,
                                                const float* __restrict__ w,
                                                const float* __restrict__ bb,
                                                float* __restrict__ outp) {
  ln_body<1, 4>(res, add, w, bb, outp);
}

extern "C" void kernel_launch(void* const* d_in, const int* in_sizes, int n_in,
                              void* d_out, int out_size, void* d_ws, size_t ws_size,
                              hipStream_t stream) {
  const float* z    = (const float*)d_in[0];
  const float* Wq   = (const float*)d_in[1];
  const float* bq   = (const float*)d_in[2];
  const float* Wk   = (const float*)d_in[3];
  const float* bk   = (const float*)d_in[4];
  const float* Wv   = (const float*)d_in[5];
  const float* bv   = (const float*)d_in[6];
  const float* Wo   = (const float*)d_in[7];
  const float* bo   = (const float*)d_in[8];
  const float* ln1w = (const float*)d_in[9];
  const float* ln1b = (const float*)d_in[10];
  const float* W1   = (const float*)d_in[11];
  const float* b1   = (const float*)d_in[12];
  const float* W2   = (const float*)d_in[13];
  const float* b2   = (const float*)d_in[14];
  const float* ln2w = (const float*)d_in[15];
  const float* ln2b = (const float*)d_in[16];
  float* out = (float*)d_out;

  char* ws = (char*)d_ws;
  size_t off = 0;
  auto alloc = [&](size_t bytes) {
    char* p = ws + off;
    off += (bytes + 255) & ~(size_t)255;
    return p;
  };
  unsigned short* Wsq   = (unsigned short*)alloc((size_t)2048 * 512 * 2);  // WqT|WkT|WvT|WoT
  unsigned short* WTqkv = Wsq;
  unsigned short* WoT   = Wsq + (size_t)1536 * 512;
  unsigned short* W1T   = (unsigned short*)alloc((size_t)2048 * 512 * 2);
  unsigned short* W2T   = (unsigned short*)alloc((size_t)512 * 2048 * 2);
  float*          biasqkv = (float*)alloc(1536 * 4);
  unsigned short* zb    = (unsigned short*)alloc((size_t)8192 * 512 * 2);
  unsigned short* z1b   = (unsigned short*)alloc((size_t)8192 * 512 * 2);
  unsigned short* qkvb  = (unsigned short*)alloc((size_t)8192 * 1536 * 2);
  unsigned short* attnb = (unsigned short*)alloc((size_t)8192 * 512 * 2);
  unsigned short* p1    = (unsigned short*)alloc((size_t)4 * 8192 * 512 * 2);  // 4 split-K planes
  unsigned short* ff    = qkvb;  // reuse qkvb+attnb (dead after Wo GEMM)

  k_prep<<<7169, 256, 0, stream>>>(z, zb, Wq, Wk, Wv, Wo, Wsq, W1, W1T, W2, W2T,
                                   bq, bk, bv, biasqkv);
  // QKV: [8192,512] @ [512,1536] -> qkvb (bf16), 192 blocks
  k_qkv<<<dim3(6, 32), 512, 0, stream>>>(zb, WTqkv, biasqkv, qkvb, 512, 1536);
  // windowed attention (2048 blocks, 32-query chunks)
  k_attn<<<2048, 64, 0, stream>>>(qkvb, attnb);
  // Wo proj: [8192,512] @ [512,512], split-K=4 -> p1[0..3], 256 blocks
  k_wo<<<dim3(2, 32, 4), 512, 0, stream>>>(attnb, WoT, bo, p1, 512, 512);
  // z1b = LN(zb + p1[0..3])  (bf16)
  k_ln_mid<<<2048, 256, 0, stream>>>(zb, p1, ln1w, ln1b, z1b);
  // FFN1: [8192,512] @ [512,2048] + GELU -> ff (bf16), 256 blocks
  k_ffn1<<<dim3(8, 32), 512, 0, stream>>>(z1b, W1T, b1, ff, 512, 2048);
  // FFN2: [8192,2048] @ [2048,512], split-K=4 -> p1[0..3], 256 blocks
  k_ffn2<<<dim3(2, 32, 4), 512, 0, stream>>>(ff, W2T, b2, p1, 2048, 512);
  // out = LN(z1b + p1[0..3])  (f32)
  k_ln_out<<<2048, 256, 0, stream>>>(z1b, p1, ln2w, ln2b, out);
}